// Round 11
// baseline (66.893 us; speedup 1.0000x reference)
//
#include <hip/hip_runtime.h>
#include <stdint.h>

#define NUM_P 8732
#define NUM_B 64
#define NUM_CLS 21
#define TOPK 200
#define NMS_T 0.45f
#define CONF_T 0.01f
#define PITCH16 8736            // NUM_P padded to /8 for ushort8 loads
#define NV8 1092                // PITCH16/8 uint4-of-8xu16 elements
#define NL2 16                  // ceil(4000/256)
#define MAXCAND 4000
#define ORD_SENT 0x407FFFFFu    // ordf(-1.0f)
#define HI_BITS 0x17800u        // (o>>15) high part common to all real scores (o>>26==47)

__device__ __forceinline__ uint32_t ordf(float f) {
    uint32_t u = __float_as_uint(f);
    return (u & 0x80000000u) ? ~u : (u | 0x80000000u);
}
__device__ __forceinline__ float unordf(uint32_t v) {
    uint32_t u = (v & 0x80000000u) ? (v ^ 0x80000000u) : ~v;
    return __uint_as_float(u);
}

// ---- Kernel A: softmax -> 16-bit score ordinals (bits [25:10]) + denom (m,s) ----
__global__ __launch_bounds__(256) void prep_kernel(const float* __restrict__ conf,
                                                   uint16_t* __restrict__ ct16,
                                                   float2* __restrict__ denom,
                                                   uint32_t* __restrict__ candCount) {
    __shared__ float tile[256 * NUM_CLS];   // 21504 B
    const int bx = blockIdx.x;
    const int b = blockIdx.y;
    const int tid = threadIdx.x;
    if (bx == 0 && b == 0 && tid < NUM_B) candCount[tid] = 0u;
    const int p0 = bx * 256;
    const int np = min(256, NUM_P - p0);
    const int nf4 = (np * NUM_CLS) / 4;     // 1344 or 147 (both exact)
    const float4* src = reinterpret_cast<const float4*>(conf + ((size_t)b * NUM_P + p0) * NUM_CLS);
    float4* dst = reinterpret_cast<float4*>(tile);
#pragma unroll
    for (int i = 0; i < 6; ++i) {
        int idx = tid + i * 256;
        if (idx < nf4) dst[idx] = src[idx];
    }
    __syncthreads();
    if (tid < np) {
        const int p = p0 + tid;
        const float* row = tile + tid * NUM_CLS;   // stride-21 LDS: 2-way conflict = free
        float x[NUM_CLS];
#pragma unroll
        for (int c = 0; c < NUM_CLS; ++c) x[c] = row[c];
        float m = x[0];
#pragma unroll
        for (int c = 1; c < NUM_CLS; ++c) m = fmaxf(m, x[c]);
        float e[NUM_CLS];
        float s = 0.0f;
#pragma unroll
        for (int c = 0; c < NUM_CLS; ++c) { e[c] = expf(x[c] - m); s += e[c]; }  // in-order
        denom[(size_t)b * NUM_P + p] = make_float2(m, s);
#pragma unroll
        for (int c = 1; c < NUM_CLS; ++c) {
            float sc = e[c] / s;
            uint16_t u = 0;    // sentinel
            if (sc > CONF_T) u = (uint16_t)((ordf(sc) >> 10) & 0xFFFFu);  // bits [25:10], >0
            ct16[((size_t)(b * 20 + (c - 1))) * PITCH16 + p] = u;
        }
    } else if (p0 + tid >= NUM_P && p0 + tid < PITCH16) {
        // pad positions p=8732..8735 -> sentinel in every column
#pragma unroll
        for (int c = 1; c < NUM_CLS; ++c)
            ct16[((size_t)(b * 20 + (c - 1))) * PITCH16 + (p0 + tid)] = 0;
    }
}

// ------- Kernel B: exact top-200 via u16 radix + exact gather + SALU-gated NMS -------
__global__ __launch_bounds__(256, 5) void select_nms_kernel(const uint16_t* __restrict__ ct16,
                                                            const float* __restrict__ conf,
                                                            const float2* __restrict__ denom,
                                                            const float* __restrict__ loc,
                                                            const float* __restrict__ priors,
                                                            float* __restrict__ selS,
                                                            float* __restrict__ selX1,
                                                            float* __restrict__ selY1,
                                                            float* __restrict__ selX2,
                                                            float* __restrict__ selY2,
                                                            uint64_t* __restrict__ cands,
                                                            uint32_t* __restrict__ candCount) {
    __shared__ uint32_t hist[2048];     // 8192 B; later: bytes 0..4799 boxes, 6144..8191 skey2
    __shared__ uint64_t skey[256];      // 2048 B
    __shared__ uint32_t plist[256];     // 1024 B selected-p list (bit31 = sentinel flag)
    __shared__ uint32_t wtot[4];
    __shared__ uint32_t sh_d, sh_above, sh_bnd, sh_nsent, sh_tcnt;
    __shared__ int scnt;
    __shared__ int sh_run;

    const int blk = blockIdx.x;
    const int b = blk / 20;
    const int c = blk % 20;
    const int tid = threadIdx.x;
    const int lane = tid & 63;
    const int wv = tid >> 6;
    const uint4* colv = reinterpret_cast<const uint4*>(ct16 + (size_t)blk * PITCH16);
    const size_t ibase = (size_t)b * NUM_P;

#pragma unroll
    for (int i = 0; i < 8; ++i) hist[tid + i * 256] = 0;
    skey[tid] = 0;
    if (tid == 0) { scnt = 0; sh_run = 0; sh_tcnt = 0; }
    __syncthreads();

    // ---- single sweep of u16 column into registers; histogram bins u16>>5 ----
    uint4 uu[5];
#pragma unroll
    for (int i = 0; i < 5; ++i) {
        int idx = tid + i * 256;
        uu[i] = make_uint4(0, 0, 0, 0);
        if (idx < NV8) uu[i] = colv[idx];
    }
    int nsent = 0;
#pragma unroll
    for (int i = 0; i < 5; ++i) {
        int idx = tid + i * 256;
        if (idx < NV8) {
            uint32_t ww[4] = {uu[i].x, uu[i].y, uu[i].z, uu[i].w};
#pragma unroll
            for (int q = 0; q < 4; ++q) {
                uint32_t lo = ww[q] & 0xFFFFu, hi = ww[q] >> 16;
                if (lo) atomicAdd(&hist[lo >> 5], 1u); else nsent++;
                if (hi) atomicAdd(&hist[hi >> 5], 1u); else nsent++;
            }
        }
    }
    {
        int v = nsent;
#pragma unroll
        for (int off = 32; off; off >>= 1) v += __shfl_down(v, off);
        if (lane == 0) wtot[wv] = (uint32_t)v;
        __syncthreads();
        if (tid == 0) sh_nsent = wtot[0] + wtot[1] + wtot[2] + wtot[3];
        __syncthreads();
    }
    const int nreal = PITCH16 - (int)sh_nsent;   // pads counted as sentinels

    int mode;                // 0 = emit >= thr16; 1 = tie path; 2 = sentinel fill
    uint32_t thr16 = 1;
    int need3 = 0, needEq = 0;

    if (nreal >= TOPK) {
        // ---- level-1 scan (2048 bins, 8/thread, suffix order) ----
        {
            const int tbase = tid * 8;
            uint32_t ls = 0;
#pragma unroll
            for (int j = 0; j < 8; ++j) ls += hist[tbase + j];
            uint32_t v = ls;
#pragma unroll
            for (int off = 1; off < 64; off <<= 1) {
                uint32_t o2 = __shfl_down(v, off);
                if (lane + off < 64) v += o2;
            }
            if (lane == 0) wtot[wv] = v;
            __syncthreads();
            uint32_t above_wave = 0;
            for (int w = wv + 1; w < 4; ++w) above_wave += wtot[w];
            uint32_t acc = (v + above_wave) - ls;
            for (int j = 7; j >= 0; --j) {
                uint32_t h = hist[tbase + j];
                if (acc < (uint32_t)TOPK && acc + h >= (uint32_t)TOPK) {
                    sh_d = (uint32_t)(tbase + j);
                    sh_above = acc;
                    sh_bnd = h;
                }
                acc += h;
            }
            __syncthreads();
        }
        uint32_t d1 = sh_d;
        int cert = (int)sh_above;
        int bnd = (int)sh_bnd;

        if (cert + bnd <= 256) {
            thr16 = d1 << 5;
            mode = 0;
        } else {
            // ---- level-2: 5-bit sub-bins within class d1 ----
            __syncthreads();
            if (tid < 32) hist[tid] = 0;
            __syncthreads();
#pragma unroll
            for (int i = 0; i < 5; ++i) {
                int idx = tid + i * 256;
                if (idx < NV8) {
                    uint32_t ww[4] = {uu[i].x, uu[i].y, uu[i].z, uu[i].w};
#pragma unroll
                    for (int q = 0; q < 4; ++q) {
                        uint32_t lo = ww[q] & 0xFFFFu, hi = ww[q] >> 16;
                        if ((lo >> 5) == d1) atomicAdd(&hist[lo & 31u], 1u);
                        if ((hi >> 5) == d1) atomicAdd(&hist[hi & 31u], 1u);
                    }
                }
            }
            __syncthreads();
            const int need = TOPK - cert;
            if (tid == 0) {
                uint32_t acc = 0;
                for (int j = 31; j >= 0; --j) {
                    uint32_t h = hist[j];
                    if (acc < (uint32_t)need && acc + h >= (uint32_t)need) {
                        sh_d = (uint32_t)j; sh_above = acc; sh_bnd = h; break;
                    }
                    acc += h;
                }
            }
            __syncthreads();
            cert += (int)sh_above;
            bnd = (int)sh_bnd;
            thr16 = (d1 << 5) | sh_d;
            if (cert + bnd <= 256) {
                mode = 0;           // emit u16 >= thr16 (exact-u16 threshold)
            } else {
                mode = 1;           // rank exact class thr16
                need3 = TOPK - cert;
            }
        }
    } else {
        mode = 2;
        thr16 = 1;                  // emit all reals
        needEq = TOPK - nreal;
    }

    // ---- emit certain selections into plist (p only; gathers later, parallel) ----
    const uint32_t emitLo = (mode == 1) ? thr16 + 1 : thr16;
#pragma unroll
    for (int i = 0; i < 5; ++i) {
        int idx = tid + i * 256;
        if (idx < NV8) {
            uint32_t ww[4] = {uu[i].x, uu[i].y, uu[i].z, uu[i].w};
#pragma unroll
            for (int q = 0; q < 4; ++q) {
                uint32_t lo = ww[q] & 0xFFFFu, hi = ww[q] >> 16;
                if (lo >= emitLo) {
                    int s0 = atomicAdd(&scnt, 1);
                    if (s0 < 256) plist[s0] = (uint32_t)(idx * 8 + q * 2);
                }
                if (hi >= emitLo) {
                    int s0 = atomicAdd(&scnt, 1);
                    if (s0 < 256) plist[s0] = (uint32_t)(idx * 8 + q * 2 + 1);
                }
            }
        }
    }
    __syncthreads();

    if (mode == 1) {
        // ---- rare: rank exact-u16 tie class by exact keys; append top-need3 ----
        // collect tie p's into hist[0..1023] (u32)
#pragma unroll
        for (int i = 0; i < 5; ++i) {
            int idx = tid + i * 256;
            if (idx < NV8) {
                uint32_t ww[4] = {uu[i].x, uu[i].y, uu[i].z, uu[i].w};
#pragma unroll
                for (int q = 0; q < 4; ++q) {
                    uint32_t lo = ww[q] & 0xFFFFu, hi = ww[q] >> 16;
                    if (lo == thr16) {
                        uint32_t t = atomicAdd(&sh_tcnt, 1u);
                        if (t < 1024u) hist[t] = (uint32_t)(idx * 8 + q * 2);
                    }
                    if (hi == thr16) {
                        uint32_t t = atomicAdd(&sh_tcnt, 1u);
                        if (t < 1024u) hist[t] = (uint32_t)(idx * 8 + q * 2 + 1);
                    }
                }
            }
        }
        __syncthreads();
        const int tn = min((int)sh_tcnt, 1024);
        uint32_t myp[4];
#pragma unroll
        for (int s = 0; s < 4; ++s) {
            int t = tid + s * 256;
            myp[s] = (t < tn) ? hist[t] : 0xFFFFFFFFu;
        }
        __syncthreads();
        uint64_t* tkey = reinterpret_cast<uint64_t*>(hist);
        uint64_t myk4[4];
#pragma unroll
        for (int s = 0; s < 4; ++s) {
            int t = tid + s * 256;
            myk4[s] = 0;
            if (t < tn) {
                uint32_t p = myp[s];
                float x = conf[(ibase + p) * NUM_CLS + (c + 1)];
                float2 ms = denom[ibase + p];
                float sc = expf(x - ms.x) / ms.y;
                uint64_t k = ((uint64_t)ordf(sc) << 32) | (0xFFFFFFFFu - p);
                tkey[t] = k;
                myk4[s] = k;
            }
        }
        __syncthreads();
#pragma unroll
        for (int s = 0; s < 4; ++s) {
            int t = tid + s * 256;
            if (t < tn) {
                uint64_t k = myk4[s];
                int r = 0;
                for (int j = 0; j < tn; ++j) r += (tkey[j] > k) ? 1 : 0;
                if (r < need3) {
                    int s0 = atomicAdd(&scnt, 1);
                    if (s0 < 256) plist[s0] = 0xFFFFFFFFu - (uint32_t)k;
                }
            }
        }
        __syncthreads();
    } else if (mode == 2) {
        // ---- rare: fewer than 200 reals; fill with lowest-p sentinels ----
        for (int i = 0; i < 5; ++i) {
            int idx = tid + i * 256;
            uint32_t flags = 0;
            int lc = 0;
            if (idx < NV8) {
                uint32_t ww[4] = {uu[i].x, uu[i].y, uu[i].z, uu[i].w};
#pragma unroll
                for (int q = 0; q < 4; ++q) {
                    uint32_t lo = ww[q] & 0xFFFFu, hi = ww[q] >> 16;
                    int p0 = idx * 8 + q * 2;
                    if (lo == 0 && p0 < NUM_P) { flags |= 1u << (q * 2); lc++; }
                    if (hi == 0 && p0 + 1 < NUM_P) { flags |= 1u << (q * 2 + 1); lc++; }
                }
            }
            uint32_t v = (uint32_t)lc;
#pragma unroll
            for (int off = 1; off < 64; off <<= 1) {
                uint32_t o2 = __shfl_up(v, off);
                if (lane >= off) v += o2;
            }
            if (lane == 63) wtot[wv] = v;
            __syncthreads();
            int woff = sh_run;
            for (int w = 0; w < wv; ++w) woff += (int)wtot[w];
            int base = woff + (int)v - lc;   // exclusive rank of my first sentinel
            int r = 0;
#pragma unroll
            for (int j = 0; j < 8; ++j) {
                if ((flags >> j) & 1u) {
                    if (base + r < needEq) {
                        int s0 = atomicAdd(&scnt, 1);
                        if (s0 < 256) plist[s0] = (uint32_t)(idx * 8 + j) | 0x80000000u;
                    }
                    r++;
                }
            }
            __syncthreads();
            if (tid == 0) sh_run += (int)(wtot[0] + wtot[1] + wtot[2] + wtot[3]);
            __syncthreads();
        }
    }

    // ---- parallel exact gather: build skey from plist ----
    const int nsel = min(scnt, 256);
    if (tid < nsel) {
        uint32_t e = plist[tid];
        uint32_t p = e & 0x7FFFFFFFu;
        uint32_t o;
        if (e & 0x80000000u) {
            o = ORD_SENT;
        } else {
            float x = conf[(ibase + p) * NUM_CLS + (c + 1)];
            float2 ms = denom[ibase + p];
            float sc = expf(x - ms.x) / ms.y;   // bit-identical to prep's arithmetic
            o = ordf(sc);
        }
        skey[tid] = ((uint64_t)o << 32) | (0xFFFFFFFFu - p);
    }
    __syncthreads();

    // ---- rank-compare sort (desc by (ordinal, p asc)) ----
    uint64_t* skey2 = reinterpret_cast<uint64_t*>(hist + 1536);   // bytes 6144..8191
    uint64_t myk = skey[tid];
    skey2[tid] = 0;
    __syncthreads();
    int rk = 0;
#pragma unroll 8
    for (int j = 0; j < 256; ++j) rk += (skey[j] > myk) ? 1 : 0;
    if (myk != 0) skey2[rk] = myk;      // keys distinct; zeros excluded
    __syncthreads();

    // ---- decode top-200 into LDS (hist bytes 0..4799; skey2 at 6144+ untouched) ----
    float4* bbox4 = reinterpret_cast<float4*>(hist);              // [200] 16B
    float*  dar   = reinterpret_cast<float*>(hist) + 4 * TOPK;    // [200]
    float*  dsc   = reinterpret_cast<float*>(hist) + 5 * TOPK;    // [200]
    uint64_t kreg = (tid < TOPK) ? skey2[tid] : 0;
    if (tid < TOPK) {
        uint32_t p = 0xFFFFFFFFu - (uint32_t)kreg;
        float msc = unordf((uint32_t)(kreg >> 32));
        const float4 l4 = reinterpret_cast<const float4*>(loc)[ibase + p];
        const float4 pr = reinterpret_cast<const float4*>(priors)[p];
        float cx = pr.x + (l4.x * 0.1f) * pr.z;
        float cy = pr.y + (l4.y * 0.1f) * pr.w;
        float w  = pr.z * expf(l4.z * 0.2f);
        float h  = pr.w * expf(l4.w * 0.2f);
        float mx1 = cx - w * 0.5f;
        float my1 = cy - h * 0.5f;
        float mx2 = mx1 + w;
        float my2 = my1 + h;
        bbox4[tid] = make_float4(mx1, my1, mx2, my2);
        dar[tid] = (mx2 - mx1 + 1.0f) * (my2 - my1 + 1.0f);
        dsc[tid] = msc;
    }
    __syncthreads();
    if (wv != 0) return;    // waves 1-3 retire; wave 0 runs the SALU-gated greedy NMS

    float jx1[4], jy1[4], jx2[4], jy2[4], jar[4], jsc[4];
    uint64_t validb[4], supb[4];
#pragma unroll
    for (int s = 0; s < 4; ++s) {
        int idx = s * 64 + lane;
        bool v = idx < TOPK;
        float4 bx = v ? bbox4[idx] : make_float4(0.f, 0.f, 0.f, 0.f);
        jx1[s] = bx.x; jy1[s] = bx.y; jx2[s] = bx.z; jy2[s] = bx.w;
        jar[s] = v ? dar[idx] : 1.0f;
        jsc[s] = v ? dsc[idx] : -1.0f;
        validb[s] = __ballot(v && jsc[s] > CONF_T);
        supb[s] = 0;
    }

#pragma unroll
    for (int s = 0; s < 4; ++s) {
        const int nown = (s == 3) ? (TOPK - 3 * 64) : 64;
#pragma unroll 1
        for (int o = 0; o < nown; ++o) {
            if (((validb[s] & ~supb[s]) >> o) & 1ull) {   // wave-uniform scalar gate
                const int i = s * 64 + o;
                const float4 bi = bbox4[i];               // LDS broadcast
                const float iar = dar[i];
#pragma unroll
                for (int s2 = s; s2 < 4; ++s2) {
                    float xx1 = fmaxf(bi.x, jx1[s2]);
                    float yy1 = fmaxf(bi.y, jy1[s2]);
                    float xx2 = fminf(bi.z, jx2[s2]);
                    float yy2 = fminf(bi.w, jy2[s2]);
                    float w = fmaxf(0.0f, xx2 - xx1 + 1.0f);
                    float h = fmaxf(0.0f, yy2 - yy1 + 1.0f);
                    float inter = w * h;
                    float iou = inter / (iar + jar[s2] - inter);
                    int idx2 = s2 * 64 + lane;
                    bool later = (s2 > s) ? (idx2 < TOPK) : (lane > o);
                    bool hit = (iou > NMS_T) && later;
                    supb[s2] |= __ballot(hit);
                }
            }
        }
    }

    // ---- compact kept rows in index order; write rows + per-image candidates ----
    const size_t base = (size_t)blk * TOPK;
    int off = 0;
    uint64_t wkey[4];
    int wrank[4];
    bool wk[4];
#pragma unroll
    for (int s = 0; s < 4; ++s) {
        uint64_t ball = validb[s] & ~supb[s];
        bool kept = (ball >> lane) & 1ull;
        int rank = off + __popcll(ball & ((1ull << lane) - 1ull));
        wk[s] = kept;
        wrank[s] = rank;
        wkey[s] = 0;
        if (kept) {
            selS[base + rank] = jsc[s];
            selX1[base + rank] = jx1[s];
            selY1[base + rank] = jy1[s];
            selX2[base + rank] = jx2[s];
            selY2[base + rank] = jy2[s];
            uint32_t pos = (uint32_t)(c + 1) * TOPK + (uint32_t)rank;
            wkey[s] = ((uint64_t)ordf(jsc[s]) << 32) | (uint32_t)(0xFFFFFFFFu - pos);
        }
        off += __popcll(ball);
    }
    uint32_t bcast = 0;
    if (lane == 0) bcast = atomicAdd(&candCount[b], (uint32_t)off);
    bcast = (uint32_t)__shfl((int)bcast, 0);
#pragma unroll
    for (int s = 0; s < 4; ++s)
        if (wk[s]) cands[(size_t)b * MAXCAND + bcast + wrank[s]] = wkey[s];
}

// ---------------- Kernel C: per-image final top-200, position-ordered ----------------
__global__ __launch_bounds__(256) void final_kernel(const uint64_t* __restrict__ cands,
                                                    const uint32_t* __restrict__ candCount,
                                                    const float* __restrict__ selS,
                                                    const float* __restrict__ selX1,
                                                    const float* __restrict__ selY1,
                                                    const float* __restrict__ selX2,
                                                    const float* __restrict__ selY2,
                                                    float* __restrict__ out) {
    __shared__ uint32_t hist[2048];
    __shared__ uint64_t skey[256];
    __shared__ uint32_t posArr[TOPK];
    __shared__ uint32_t sortedPos[TOPK];
    __shared__ uint32_t wtot[4];
    __shared__ int wsum[2][4];
    __shared__ uint32_t sh_d, sh_above, sh_bnd;
    __shared__ int scnt;

    const int b = blockIdx.x;
    const int tid = threadIdx.x;
    const int lane = tid & 63;
    const int wv = tid >> 6;
    const int n = (int)candCount[b];

    uint64_t key[NL2];
#pragma unroll
    for (int i = 0; i < NL2; ++i) {
        int idx = tid + i * 256;
        key[i] = (idx < n) ? cands[(size_t)b * MAXCAND + idx] : 0ull;
    }
#pragma unroll
    for (int i = 0; i < 8; ++i) hist[tid + i * 256] = 0;
    skey[tid] = 0;
    if (tid == 0) scnt = 0;
    __syncthreads();

    uint64_t emitThr = 1;   // n<=200: emit all nonzero
    if (n > TOPK) {
#pragma unroll
        for (int i = 0; i < NL2; ++i)
            if (key[i] != 0ull) atomicAdd(&hist[(uint32_t)(key[i] >> 47) & 2047u], 1u);
        __syncthreads();
        {
            const int tbase = tid * 8;
            uint32_t ls = 0;
#pragma unroll
            for (int j = 0; j < 8; ++j) ls += hist[tbase + j];
            uint32_t v = ls;
#pragma unroll
            for (int off = 1; off < 64; off <<= 1) {
                uint32_t o2 = __shfl_down(v, off);
                if (lane + off < 64) v += o2;
            }
            if (lane == 0) wtot[wv] = v;
            __syncthreads();
            uint32_t above_wave = 0;
            for (int w = wv + 1; w < 4; ++w) above_wave += wtot[w];
            uint32_t acc = (v + above_wave) - ls;
            for (int j = 7; j >= 0; --j) {
                uint32_t h = hist[tbase + j];
                if (acc < (uint32_t)TOPK && acc + h >= (uint32_t)TOPK) {
                    sh_d = (uint32_t)(tbase + j);
                    sh_above = acc;
                    sh_bnd = h;
                }
                acc += h;
            }
            __syncthreads();
        }
        if (sh_above + sh_bnd <= 256u) {
            emitThr = (uint64_t)(HI_BITS | sh_d) << 47;
        } else {
            uint64_t prefix = 0;
            for (int bit = 63; bit >= 0; --bit) {
                uint64_t cand = prefix | (1ull << bit);
                int cnt = 0;
#pragma unroll
                for (int i = 0; i < NL2; ++i) cnt += (key[i] >= cand) ? 1 : 0;
                for (int off = 32; off; off >>= 1) cnt += __shfl_down(cnt, off);
                int bufi = bit & 1;
                if (lane == 0) wsum[bufi][wv] = cnt;
                __syncthreads();
                int tot = wsum[bufi][0] + wsum[bufi][1] + wsum[bufi][2] + wsum[bufi][3];
                if (tot >= TOPK) prefix = cand;
            }
            emitThr = prefix;   // exactly 200 keys >= prefix (keys distinct)
        }
    }

#pragma unroll
    for (int i = 0; i < NL2; ++i) {
        if (key[i] != 0ull && key[i] >= emitThr) {
            int s0 = atomicAdd(&scnt, 1);
            if (s0 < 256) skey[s0] = key[i];
        }
    }
    __syncthreads();
    const int nsel = min(scnt, TOPK);

    uint64_t myk = skey[tid];
    __syncthreads();
    int rk = 0;
#pragma unroll 8
    for (int j = 0; j < 256; ++j) rk += (skey[j] > myk) ? 1 : 0;
    if (myk != 0 && rk < TOPK) posArr[rk] = 0xFFFFFFFFu - (uint32_t)myk;
    __syncthreads();

    if (tid < nsel) {
        uint32_t mypos = posArr[tid];
        int pr = 0;
        for (int j = 0; j < nsel; ++j) pr += (posArr[j] < mypos) ? 1 : 0;
        sortedPos[pr] = mypos;
    }
    __syncthreads();

    if (tid < TOPK) {
        int T = TOPK - nsel;
        float* o = out + ((size_t)b * TOPK + tid) * 7;
        if (tid < T) {
            o[0] = 0.f; o[1] = 0.f; o[2] = 0.f; o[3] = 0.f; o[4] = 0.f; o[5] = 0.f; o[6] = 0.f;
        } else {
            uint32_t pos = sortedPos[tid - T];
            uint32_t cc = pos / TOPK;
            uint32_t sl = pos % TOPK;
            size_t r = ((size_t)b * 20 + (cc - 1)) * TOPK + sl;
            o[0] = selS[r]; o[1] = selX1[r]; o[2] = selY1[r]; o[3] = selX2[r]; o[4] = selY2[r];
            o[5] = 0.f; o[6] = 0.f;
        }
    }
}

extern "C" void kernel_launch(void* const* d_in, const int* in_sizes, int n_in,
                              void* d_out, int out_size, void* d_ws, size_t ws_size,
                              hipStream_t stream) {
    const float* loc    = (const float*)d_in[0];
    const float* conf   = (const float*)d_in[1];
    const float* priors = (const float*)d_in[2];
    float* out = (float*)d_out;

    const size_t CAND_BYTES  = (size_t)NUM_B * MAXCAND * sizeof(uint64_t);     // 2,048,000
    const size_t SEL_ONE     = (size_t)NUM_B * 20 * TOPK * sizeof(float);      // 1,024,000
    const size_t CNT_BYTES   = 256;
    const size_t DENOM_BYTES = (size_t)NUM_B * NUM_P * sizeof(float2);         // 4,470,784

    char* ws = (char*)d_ws;
    uint64_t* cands     = (uint64_t*)ws;
    float*    selS      = (float*)(ws + CAND_BYTES);
    float*    selX1     = (float*)(ws + CAND_BYTES + SEL_ONE);
    float*    selY1     = (float*)(ws + CAND_BYTES + 2 * SEL_ONE);
    float*    selX2     = (float*)(ws + CAND_BYTES + 3 * SEL_ONE);
    float*    selY2     = (float*)(ws + CAND_BYTES + 4 * SEL_ONE);
    uint32_t* candCount = (uint32_t*)(ws + CAND_BYTES + 5 * SEL_ONE);
    float2*   denom     = (float2*)(ws + CAND_BYTES + 5 * SEL_ONE + CNT_BYTES);
    uint16_t* ct16      = (uint16_t*)(ws + CAND_BYTES + 5 * SEL_ONE + CNT_BYTES + DENOM_BYTES);

    dim3 pgrid(35, NUM_B);
    prep_kernel<<<pgrid, 256, 0, stream>>>(conf, ct16, denom, candCount);
    select_nms_kernel<<<NUM_B * 20, 256, 0, stream>>>(ct16, conf, denom, loc, priors,
                                                      selS, selX1, selY1, selX2, selY2,
                                                      cands, candCount);
    final_kernel<<<NUM_B, 256, 0, stream>>>(cands, candCount,
                                            selS, selX1, selY1, selX2, selY2, out);
}

// Round 12
// 63.653 us; speedup vs baseline: 1.0509x; 1.0509x over previous
//
#include <hip/hip_runtime.h>
#include <stdint.h>

#define NUM_P 8732
#define NUM_B 64
#define NUM_CLS 21
#define TOPK 200
#define NMS_T 0.45f
#define CONF_T 0.01f
#define NL 35               // ceil(8732/256) scalar sweep iters
#define NV4 2183            // 8732/4 uint4 sweep elements
#define NL2 16              // ceil(4000/256)
#define MAXCAND 4000
#define ORD_SENT 0x407FFFFFu   // ordf(-1.0f)
#define HI_BITS 0x17800u       // (o>>15) high part common to all real scores (o>>26==47)

__device__ __forceinline__ uint32_t ordf(float f) {
    uint32_t u = __float_as_uint(f);
    return (u & 0x80000000u) ? ~u : (u | 0x80000000u);
}
__device__ __forceinline__ float unordf(uint32_t v) {
    uint32_t u = (v & 0x80000000u) ? (v ^ 0x80000000u) : ~v;
    return __uint_as_float(u);
}

// ---------------- Kernel A: softmax -> transposed score ordinals (LDS-staged) --------
__global__ __launch_bounds__(256) void prep_kernel(const float* __restrict__ conf,
                                                   uint32_t* __restrict__ ct,
                                                   uint32_t* __restrict__ candCount) {
    __shared__ float tile[256 * NUM_CLS];   // 21504 B
    const int bx = blockIdx.x;
    const int b = blockIdx.y;
    const int tid = threadIdx.x;
    if (bx == 0 && b == 0 && tid < NUM_B) candCount[tid] = 0u;
    const int p0 = bx * 256;
    const int np = min(256, NUM_P - p0);
    const int nf4 = (np * NUM_CLS) / 4;     // 1344 or 147 (both exact)
    const float4* src = reinterpret_cast<const float4*>(conf + ((size_t)b * NUM_P + p0) * NUM_CLS);
    float4* dst = reinterpret_cast<float4*>(tile);
#pragma unroll
    for (int i = 0; i < 6; ++i) {
        int idx = tid + i * 256;
        if (idx < nf4) dst[idx] = src[idx];
    }
    __syncthreads();
    if (tid < np) {
        const int p = p0 + tid;
        const float* row = tile + tid * NUM_CLS;   // stride-21 LDS: 2-way conflict = free
        float x[NUM_CLS];
#pragma unroll
        for (int c = 0; c < NUM_CLS; ++c) x[c] = row[c];
        float m = x[0];
#pragma unroll
        for (int c = 1; c < NUM_CLS; ++c) m = fmaxf(m, x[c]);
        float e[NUM_CLS];
        float s = 0.0f;
#pragma unroll
        for (int c = 0; c < NUM_CLS; ++c) { e[c] = expf(x[c] - m); s += e[c]; }  // in-order
#pragma unroll
        for (int c = 1; c < NUM_CLS; ++c) {
            float sc = e[c] / s;
            float sv = (sc > CONF_T) ? sc : -1.0f;
            ct[((size_t)(b * 20 + (c - 1))) * NUM_P + p] = ordf(sv);
        }
    }
}

// ------- Kernel B: per-(image,class) exact top-200 + decode + SALU-gated NMS -------
// grid = 1280 = exactly 5 blocks/CU; launch_bounds(256,5) makes all co-resident.
__global__ __launch_bounds__(256, 5) void select_nms_kernel(const uint32_t* __restrict__ ct,
                                                            const float* __restrict__ loc,
                                                            const float* __restrict__ priors,
                                                            float* __restrict__ selS,
                                                            float* __restrict__ selX1,
                                                            float* __restrict__ selY1,
                                                            float* __restrict__ selX2,
                                                            float* __restrict__ selY2,
                                                            uint64_t* __restrict__ cands,
                                                            uint32_t* __restrict__ candCount) {
    __shared__ uint32_t hist[2048];         // 8192 B; bytes 0..4799 reused for boxes,
                                            // bytes 6144..8191 reused as skey2
    __shared__ uint64_t skey[256];          // 2048 B
    __shared__ uint32_t wtot[4];
    __shared__ uint32_t sh_d, sh_above, sh_bnd, sh_nsent;
    __shared__ int scnt;
    __shared__ int sh_run;

    const int blk = blockIdx.x;
    const int b = blk / 20;
    const int c = blk % 20;
    const int tid = threadIdx.x;
    const int lane = tid & 63;
    const int wv = tid >> 6;
    const uint32_t* col = ct + (size_t)blk * NUM_P;
    const uint4* colv = reinterpret_cast<const uint4*>(col);

#pragma unroll
    for (int i = 0; i < 8; ++i) hist[tid + i * 256] = 0;
    skey[tid] = 0;
    if (tid == 0) { scnt = 0; sh_run = 0; }
    __syncthreads();

    // ---- single global sweep into registers; histogram bits [25:15] + sentinels ----
    uint4 vv[9];
#pragma unroll
    for (int i = 0; i < 9; ++i) {
        int idx = tid + i * 256;
        vv[i] = make_uint4(ORD_SENT, ORD_SENT, ORD_SENT, ORD_SENT);
        if (idx < NV4) vv[i] = colv[idx];
    }
    int nsent = 0;
#pragma unroll
    for (int i = 0; i < 9; ++i) {
        int idx = tid + i * 256;
        if (idx < NV4) {
            uint32_t a0 = vv[i].x, a1 = vv[i].y, a2 = vv[i].z, a3 = vv[i].w;
            if (a0 == ORD_SENT) nsent++; else atomicAdd(&hist[(a0 >> 15) & 2047u], 1u);
            if (a1 == ORD_SENT) nsent++; else atomicAdd(&hist[(a1 >> 15) & 2047u], 1u);
            if (a2 == ORD_SENT) nsent++; else atomicAdd(&hist[(a2 >> 15) & 2047u], 1u);
            if (a3 == ORD_SENT) nsent++; else atomicAdd(&hist[(a3 >> 15) & 2047u], 1u);
        }
    }
    {
        int v = nsent;
#pragma unroll
        for (int off = 32; off; off >>= 1) v += __shfl_down(v, off);
        if (lane == 0) wtot[wv] = (uint32_t)v;
        __syncthreads();
        if (tid == 0) sh_nsent = wtot[0] + wtot[1] + wtot[2] + wtot[3];
        __syncthreads();
    }
    const int nreal = NUM_P - (int)sh_nsent;

    uint32_t emitThr = 0;
    bool ranked = false;
    uint32_t thrEq = 0;
    int needEq = 0;

    if (nreal >= TOPK) {
        // ---- level-1 scan (2048 bins, 8/thread, suffix order) ----
        {
            const int tbase = tid * 8;
            uint32_t ls = 0;
#pragma unroll
            for (int j = 0; j < 8; ++j) ls += hist[tbase + j];
            uint32_t v = ls;
#pragma unroll
            for (int off = 1; off < 64; off <<= 1) {
                uint32_t o2 = __shfl_down(v, off);
                if (lane + off < 64) v += o2;
            }
            if (lane == 0) wtot[wv] = v;
            __syncthreads();
            uint32_t above_wave = 0;
            for (int w = wv + 1; w < 4; ++w) above_wave += wtot[w];
            uint32_t acc = (v + above_wave) - ls;
            for (int j = 7; j >= 0; --j) {
                uint32_t h = hist[tbase + j];
                if (acc < (uint32_t)TOPK && acc + h >= (uint32_t)TOPK) {
                    sh_d = (uint32_t)(tbase + j);
                    sh_above = acc;
                    sh_bnd = h;
                }
                acc += h;
            }
            __syncthreads();
        }
        uint32_t d1 = sh_d;
        int cert = (int)sh_above;
        int need = TOPK - cert;
        int bnd = (int)sh_bnd;
        const uint32_t lvl1 = HI_BITS | d1;

        if (cert + bnd <= 256) {
            emitThr = lvl1 << 15;
        } else {
            // ---- level-2: bits [14:4] among (o>>15)==lvl1 (from registers) ----
            __syncthreads();
#pragma unroll
            for (int i = 0; i < 8; ++i) hist[tid + i * 256] = 0;
            __syncthreads();
#pragma unroll
            for (int i = 0; i < 9; ++i) {
                int idx = tid + i * 256;
                if (idx < NV4) {
                    if ((vv[i].x >> 15) == lvl1) atomicAdd(&hist[(vv[i].x >> 4) & 2047u], 1u);
                    if ((vv[i].y >> 15) == lvl1) atomicAdd(&hist[(vv[i].y >> 4) & 2047u], 1u);
                    if ((vv[i].z >> 15) == lvl1) atomicAdd(&hist[(vv[i].z >> 4) & 2047u], 1u);
                    if ((vv[i].w >> 15) == lvl1) atomicAdd(&hist[(vv[i].w >> 4) & 2047u], 1u);
                }
            }
            __syncthreads();
            {
                const int tbase = tid * 8;
                uint32_t ls = 0;
#pragma unroll
                for (int j = 0; j < 8; ++j) ls += hist[tbase + j];
                uint32_t v = ls;
#pragma unroll
                for (int off = 1; off < 64; off <<= 1) {
                    uint32_t o2 = __shfl_down(v, off);
                    if (lane + off < 64) v += o2;
                }
                if (lane == 0) wtot[wv] = v;
                __syncthreads();
                uint32_t above_wave = 0;
                for (int w = wv + 1; w < 4; ++w) above_wave += wtot[w];
                uint32_t acc = (v + above_wave) - ls;
                for (int j = 7; j >= 0; --j) {
                    uint32_t h = hist[tbase + j];
                    if (acc < (uint32_t)need && acc + h >= (uint32_t)need) {
                        sh_d = (uint32_t)(tbase + j);
                        sh_above = acc;
                        sh_bnd = h;
                    }
                    acc += h;
                }
                __syncthreads();
            }
            uint32_t d2 = sh_d;
            cert += (int)sh_above;
            need -= (int)sh_above;
            bnd = (int)sh_bnd;
            const uint32_t pfx28 = (lvl1 << 11) | d2;

            if (cert + bnd <= 256) {
                emitThr = pfx28 << 4;
            } else {
                // ---- level-3: low 4 bits among (o>>4)==pfx28 ----
                __syncthreads();
                if (tid < 16) hist[tid] = 0;
                __syncthreads();
#pragma unroll
                for (int i = 0; i < 9; ++i) {
                    int idx = tid + i * 256;
                    if (idx < NV4) {
                        if ((vv[i].x >> 4) == pfx28) atomicAdd(&hist[vv[i].x & 15u], 1u);
                        if ((vv[i].y >> 4) == pfx28) atomicAdd(&hist[vv[i].y & 15u], 1u);
                        if ((vv[i].z >> 4) == pfx28) atomicAdd(&hist[vv[i].z & 15u], 1u);
                        if ((vv[i].w >> 4) == pfx28) atomicAdd(&hist[vv[i].w & 15u], 1u);
                    }
                }
                __syncthreads();
                if (tid == 0) {
                    uint32_t acc = 0;
                    for (int j = 15; j >= 0; --j) {
                        uint32_t h = hist[j];
                        if (acc < (uint32_t)need && acc + h >= (uint32_t)need) {
                            sh_d = (uint32_t)j; sh_above = acc; sh_bnd = h; break;
                        }
                        acc += h;
                    }
                }
                __syncthreads();
                uint32_t d3 = sh_d;
                cert += (int)sh_above;
                need -= (int)sh_above;
                bnd = (int)sh_bnd;
                const uint32_t pfx32 = (pfx28 << 4) | d3;
                if (cert + bnd <= 256) {
                    emitThr = pfx32;
                } else {
                    ranked = true; thrEq = pfx32; needEq = need;
                }
            }
        }
    } else {
        ranked = true; thrEq = ORD_SENT; needEq = TOPK - nreal;
    }

    // ---- emit ----
    if (!ranked) {
#pragma unroll
        for (int i = 0; i < 9; ++i) {
            int idx = tid + i * 256;
            if (idx < NV4) {
                uint32_t aa[4] = {vv[i].x, vv[i].y, vv[i].z, vv[i].w};
#pragma unroll
                for (int j = 0; j < 4; ++j) {
                    uint32_t o = aa[j];
                    if (o >= emitThr) {
                        int s0 = atomicAdd(&scnt, 1);
                        uint32_t p = (uint32_t)(idx * 4 + j);
                        if (s0 < 256)
                            skey[s0] = ((uint64_t)o << 32) | (0xFFFFFFFFu - p);
                    }
                }
            }
        }
        __syncthreads();
    } else {
        // exact ranked-tie path (rare): p-ascending global order via ballot scan
        for (int i = 0; i < NL; ++i) {
            int p = i * 256 + tid;
            uint32_t o = (p < NUM_P) ? col[p] : 0u;
            if (o > thrEq) {
                int s0 = atomicAdd(&scnt, 1);
                if (s0 < 256)
                    skey[s0] = ((uint64_t)o << 32) | (0xFFFFFFFFu - (uint32_t)p);
            }
            bool tie = (p < NUM_P) && (o == thrEq);
            unsigned long long ball = __ballot(tie);
            if (lane == 0) wtot[wv] = (uint32_t)__popcll(ball);
            __syncthreads();
            int rank = sh_run;
            for (int w = 0; w < wv; ++w) rank += (int)wtot[w];
            rank += __popcll(ball & ((1ull << lane) - 1ull));
            if (tie && rank < needEq) {
                int s0 = atomicAdd(&scnt, 1);
                if (s0 < 256)
                    skey[s0] = ((uint64_t)o << 32) | (0xFFFFFFFFu - (uint32_t)p);
            }
            __syncthreads();
            if (tid == 0) sh_run += (int)(wtot[0] + wtot[1] + wtot[2] + wtot[3]);
            __syncthreads();
        }
    }

    // ---- rank-compare sort (desc by (ordinal, p asc)); 2 barriers, no bitonic ----
    uint64_t* skey2 = reinterpret_cast<uint64_t*>(hist + 1536);   // bytes 6144..8191
    uint64_t myk = skey[tid];
    skey2[tid] = 0;
    __syncthreads();
    int rk = 0;
#pragma unroll 8
    for (int j = 0; j < 256; ++j) rk += (skey[j] > myk) ? 1 : 0;
    if (myk != 0) skey2[rk] = myk;      // keys distinct; zeros excluded
    __syncthreads();

    // ---- decode top-200 into LDS (hist bytes 0..4799; skey2 at 6144+ untouched) ----
    float4* bbox4 = reinterpret_cast<float4*>(hist);              // [200] 16B
    float*  dar   = reinterpret_cast<float*>(hist) + 4 * TOPK;    // [200]
    float*  dsc   = reinterpret_cast<float*>(hist) + 5 * TOPK;    // [200]
    uint64_t kreg = (tid < TOPK) ? skey2[tid] : 0;
    if (tid < TOPK) {
        uint32_t p = 0xFFFFFFFFu - (uint32_t)kreg;
        float msc = unordf((uint32_t)(kreg >> 32));
        const float4 l4 = reinterpret_cast<const float4*>(loc)[(size_t)b * NUM_P + p];
        const float4 pr = reinterpret_cast<const float4*>(priors)[p];
        float cx = pr.x + (l4.x * 0.1f) * pr.z;
        float cy = pr.y + (l4.y * 0.1f) * pr.w;
        float w  = pr.z * expf(l4.z * 0.2f);
        float h  = pr.w * expf(l4.w * 0.2f);
        float mx1 = cx - w * 0.5f;
        float my1 = cy - h * 0.5f;
        float mx2 = mx1 + w;
        float my2 = my1 + h;
        bbox4[tid] = make_float4(mx1, my1, mx2, my2);
        dar[tid] = (mx2 - mx1 + 1.0f) * (my2 - my1 + 1.0f);
        dsc[tid] = msc;
    }
    __syncthreads();
    if (wv != 0) return;    // waves 1-3 retire; wave 0 runs the SALU-gated greedy NMS

    // ---- j-side register copies; valid/sup as wave-uniform ballot masks (SGPRs) ----
    float jx1[4], jy1[4], jx2[4], jy2[4], jar[4], jsc[4];
    uint64_t validb[4], supb[4];
#pragma unroll
    for (int s = 0; s < 4; ++s) {
        int idx = s * 64 + lane;
        bool v = idx < TOPK;
        float4 bx = v ? bbox4[idx] : make_float4(0.f, 0.f, 0.f, 0.f);
        jx1[s] = bx.x; jy1[s] = bx.y; jx2[s] = bx.z; jy2[s] = bx.w;
        jar[s] = v ? dar[idx] : 1.0f;
        jsc[s] = v ? dsc[idx] : -1.0f;
        validb[s] = __ballot(v && jsc[s] > CONF_T);
        supb[s] = 0;
    }

    // greedy: scalar keep-test (s_lshr/s_and/s_cbranch), gated IoU only for j >= i
#pragma unroll
    for (int s = 0; s < 4; ++s) {
        const int nown = (s == 3) ? (TOPK - 3 * 64) : 64;
#pragma unroll 1
        for (int o = 0; o < nown; ++o) {
            if (((validb[s] & ~supb[s]) >> o) & 1ull) {   // wave-uniform scalar gate
                const int i = s * 64 + o;
                const float4 bi = bbox4[i];               // LDS broadcast
                const float iar = dar[i];
#pragma unroll
                for (int s2 = s; s2 < 4; ++s2) {
                    float xx1 = fmaxf(bi.x, jx1[s2]);
                    float yy1 = fmaxf(bi.y, jy1[s2]);
                    float xx2 = fminf(bi.z, jx2[s2]);
                    float yy2 = fminf(bi.w, jy2[s2]);
                    float w = fmaxf(0.0f, xx2 - xx1 + 1.0f);
                    float h = fmaxf(0.0f, yy2 - yy1 + 1.0f);
                    float inter = w * h;
                    float iou = inter / (iar + jar[s2] - inter);
                    int idx2 = s2 * 64 + lane;
                    bool later = (s2 > s) ? (idx2 < TOPK) : (lane > o);
                    bool hit = (iou > NMS_T) && later;
                    supb[s2] |= __ballot(hit);
                }
            }
        }
    }

    // ---- compact kept rows in index order; write rows + per-image candidates ----
    const size_t base = (size_t)blk * TOPK;
    int off = 0;
    uint64_t wkey[4];
    int wrank[4];
    bool wk[4];
#pragma unroll
    for (int s = 0; s < 4; ++s) {
        uint64_t ball = validb[s] & ~supb[s];
        bool kept = (ball >> lane) & 1ull;
        int rank = off + __popcll(ball & ((1ull << lane) - 1ull));
        wk[s] = kept;
        wrank[s] = rank;
        wkey[s] = 0;
        if (kept) {
            selS[base + rank] = jsc[s];
            selX1[base + rank] = jx1[s];
            selY1[base + rank] = jy1[s];
            selX2[base + rank] = jx2[s];
            selY2[base + rank] = jy2[s];
            uint32_t pos = (uint32_t)(c + 1) * TOPK + (uint32_t)rank;
            wkey[s] = ((uint64_t)ordf(jsc[s]) << 32) | (uint32_t)(0xFFFFFFFFu - pos);
        }
        off += __popcll(ball);
    }
    uint32_t bcast = 0;
    if (lane == 0) bcast = atomicAdd(&candCount[b], (uint32_t)off);
    bcast = (uint32_t)__shfl((int)bcast, 0);
#pragma unroll
    for (int s = 0; s < 4; ++s)
        if (wk[s]) cands[(size_t)b * MAXCAND + bcast + wrank[s]] = wkey[s];
}

// ---------------- Kernel C: per-image final top-200, position-ordered ----------------
__global__ __launch_bounds__(256) void final_kernel(const uint64_t* __restrict__ cands,
                                                    const uint32_t* __restrict__ candCount,
                                                    const float* __restrict__ selS,
                                                    const float* __restrict__ selX1,
                                                    const float* __restrict__ selY1,
                                                    const float* __restrict__ selX2,
                                                    const float* __restrict__ selY2,
                                                    float* __restrict__ out) {
    __shared__ uint32_t hist[2048];
    __shared__ uint64_t skey[256];
    __shared__ uint32_t posArr[TOPK];
    __shared__ uint32_t sortedPos[TOPK];
    __shared__ uint32_t wtot[4];
    __shared__ int wsum[2][4];
    __shared__ uint32_t sh_d, sh_above, sh_bnd;
    __shared__ int scnt;

    const int b = blockIdx.x;
    const int tid = threadIdx.x;
    const int lane = tid & 63;
    const int wv = tid >> 6;
    const int n = (int)candCount[b];

    uint64_t key[NL2];
#pragma unroll
    for (int i = 0; i < NL2; ++i) {
        int idx = tid + i * 256;
        key[i] = (idx < n) ? cands[(size_t)b * MAXCAND + idx] : 0ull;
    }
#pragma unroll
    for (int i = 0; i < 8; ++i) hist[tid + i * 256] = 0;
    skey[tid] = 0;
    if (tid == 0) scnt = 0;
    __syncthreads();

    uint64_t emitThr = 1;   // n<=200: emit all nonzero
    if (n > TOPK) {
        // histogram of highword bits [25:15] (all cand scores are real: > CONF_T)
#pragma unroll
        for (int i = 0; i < NL2; ++i)
            if (key[i] != 0ull) atomicAdd(&hist[(uint32_t)(key[i] >> 47) & 2047u], 1u);
        __syncthreads();
        {
            const int tbase = tid * 8;
            uint32_t ls = 0;
#pragma unroll
            for (int j = 0; j < 8; ++j) ls += hist[tbase + j];
            uint32_t v = ls;
#pragma unroll
            for (int off = 1; off < 64; off <<= 1) {
                uint32_t o2 = __shfl_down(v, off);
                if (lane + off < 64) v += o2;
            }
            if (lane == 0) wtot[wv] = v;
            __syncthreads();
            uint32_t above_wave = 0;
            for (int w = wv + 1; w < 4; ++w) above_wave += wtot[w];
            uint32_t acc = (v + above_wave) - ls;
            for (int j = 7; j >= 0; --j) {
                uint32_t h = hist[tbase + j];
                if (acc < (uint32_t)TOPK && acc + h >= (uint32_t)TOPK) {
                    sh_d = (uint32_t)(tbase + j);
                    sh_above = acc;
                    sh_bnd = h;
                }
                acc += h;
            }
            __syncthreads();
        }
        if (sh_above + sh_bnd <= 256u) {
            emitThr = (uint64_t)(HI_BITS | sh_d) << 47;
        } else {
            // rare fat-boundary fallback: exact 64-step bit descent for the 200th key
            uint64_t prefix = 0;
            for (int bit = 63; bit >= 0; --bit) {
                uint64_t cand = prefix | (1ull << bit);
                int cnt = 0;
#pragma unroll
                for (int i = 0; i < NL2; ++i) cnt += (key[i] >= cand) ? 1 : 0;
                for (int off = 32; off; off >>= 1) cnt += __shfl_down(cnt, off);
                int bufi = bit & 1;
                if (lane == 0) wsum[bufi][wv] = cnt;
                __syncthreads();
                int tot = wsum[bufi][0] + wsum[bufi][1] + wsum[bufi][2] + wsum[bufi][3];
                if (tot >= TOPK) prefix = cand;
            }
            emitThr = prefix;   // exactly 200 keys >= prefix (keys distinct)
        }
    }

    // ---- emit candidates >= threshold ----
#pragma unroll
    for (int i = 0; i < NL2; ++i) {
        if (key[i] != 0ull && key[i] >= emitThr) {
            int s0 = atomicAdd(&scnt, 1);
            if (s0 < 256) skey[s0] = key[i];
        }
    }
    __syncthreads();
    const int nsel = min(scnt, TOPK);

    // ---- rank-compare: top-200 by key desc -> posArr[rank] ----
    uint64_t myk = skey[tid];
    __syncthreads();
    int rk = 0;
#pragma unroll 8
    for (int j = 0; j < 256; ++j) rk += (skey[j] > myk) ? 1 : 0;
    if (myk != 0 && rk < TOPK) posArr[rk] = 0xFFFFFFFFu - (uint32_t)myk;
    __syncthreads();

    // ---- rank-compare: order selected positions ascending ----
    if (tid < nsel) {
        uint32_t mypos = posArr[tid];
        int pr = 0;
        for (int j = 0; j < nsel; ++j) pr += (posArr[j] < mypos) ? 1 : 0;
        sortedPos[pr] = mypos;
    }
    __syncthreads();

    if (tid < TOPK) {
        int T = TOPK - nsel;
        float* o = out + ((size_t)b * TOPK + tid) * 7;
        if (tid < T) {
            o[0] = 0.f; o[1] = 0.f; o[2] = 0.f; o[3] = 0.f; o[4] = 0.f; o[5] = 0.f; o[6] = 0.f;
        } else {
            uint32_t pos = sortedPos[tid - T];
            uint32_t cc = pos / TOPK;
            uint32_t sl = pos % TOPK;
            size_t r = ((size_t)b * 20 + (cc - 1)) * TOPK + sl;
            o[0] = selS[r]; o[1] = selX1[r]; o[2] = selY1[r]; o[3] = selX2[r]; o[4] = selY2[r];
            o[5] = 0.f; o[6] = 0.f;
        }
    }
}

extern "C" void kernel_launch(void* const* d_in, const int* in_sizes, int n_in,
                              void* d_out, int out_size, void* d_ws, size_t ws_size,
                              hipStream_t stream) {
    const float* loc    = (const float*)d_in[0];
    const float* conf   = (const float*)d_in[1];
    const float* priors = (const float*)d_in[2];
    float* out = (float*)d_out;

    const size_t CAND_BYTES = (size_t)NUM_B * MAXCAND * sizeof(uint64_t);   // 2,048,000
    const size_t SEL_ONE    = (size_t)NUM_B * 20 * TOPK * sizeof(float);    // 1,024,000
    const size_t CNT_BYTES  = 256;

    char* ws = (char*)d_ws;
    uint64_t* cands     = (uint64_t*)ws;
    float*    selS      = (float*)(ws + CAND_BYTES);
    float*    selX1     = (float*)(ws + CAND_BYTES + SEL_ONE);
    float*    selY1     = (float*)(ws + CAND_BYTES + 2 * SEL_ONE);
    float*    selX2     = (float*)(ws + CAND_BYTES + 3 * SEL_ONE);
    float*    selY2     = (float*)(ws + CAND_BYTES + 4 * SEL_ONE);
    uint32_t* candCount = (uint32_t*)(ws + CAND_BYTES + 5 * SEL_ONE);
    uint32_t* ct        = (uint32_t*)(ws + CAND_BYTES + 5 * SEL_ONE + CNT_BYTES);

    dim3 pgrid(35, NUM_B);
    prep_kernel<<<pgrid, 256, 0, stream>>>(conf, ct, candCount);
    select_nms_kernel<<<NUM_B * 20, 256, 0, stream>>>(ct, loc, priors,
                                                      selS, selX1, selY1, selX2, selY2,
                                                      cands, candCount);
    final_kernel<<<NUM_B, 256, 0, stream>>>(cands, candCount,
                                            selS, selX1, selY1, selX2, selY2, out);
}